// Round 4
// baseline (350.731 us; speedup 1.0000x reference)
//
#include <hip/hip_runtime.h>
#include <math.h>

#define H_ 128
#define W_ 128
#define C_ 64
#define O_ 64
#define B_ 8
#define K2_ 9
#define HWSZ (H_*W_)

// 8-byte vector load with only 4-byte alignment guarantee (column-pair merge).
typedef float f2u __attribute__((ext_vector_type(2), aligned(4)));

// ---------------------------------------------------------------------------
// Kernel P: weight prep.
//  wt  (K2, C, O)  : sample-GEMM weights, contiguous in o -> clean s_load.
//  wom (C, 27, 9)  : offset(18)+mask(9) conv weights contiguous per channel.
// ---------------------------------------------------------------------------
__global__ __launch_bounds__(256) void prep_weights_k(
    const float* __restrict__ w, const float* __restrict__ w_off,
    const float* __restrict__ w_mod, float* __restrict__ wt,
    float* __restrict__ wom) {
    int id = blockIdx.x * 256 + threadIdx.x;
    if (id < K2_ * C_ * O_) {              // id = k*C*O + c*O + o
        int o = id & (O_ - 1);
        int c = (id >> 6) & (C_ - 1);
        int k = id / (C_ * O_);
        wt[id] = w[(o * C_ + c) * K2_ + k];
    }
    int id2 = id - K2_ * C_ * O_;
    if (id2 >= 0 && id2 < C_ * 243) {      // id2 = c*243 + t*9 + k
        int k = id2 % 9;
        int tt = (id2 / 9) % 27;
        int c = id2 / 243;
        float v = (tt < 18) ? w_off[(tt * C_ + c) * K2_ + k]
                            : w_mod[((tt - 18) * C_ + c) * K2_ + k];
        wom[id2] = v;
    }
}

// ---------------------------------------------------------------------------
// Fused kernel: phase A (offset/mask 3x3 conv) + phase B (bilinear sample +
// reduction GEMM) in one dispatch.
//
// Round-3 lessons driving this design:
//  - Phase B is at the TA roofline for its divergence pattern (~47 cy per
//    wave-gather, 9216 gathers/CU -> ~180 us). Its structure is kept
//    byte-identical (dwordx2 column-pair merge, edge-folded weights,
//    2-way c-split, 64KB LDS o-reduce).
//  - Standalone kernel A ran ~125 us vs a ~26 us VALU floor (weight s_load
//    stream stalls, no overlap with B). Fused, phase-A FMAs of co-resident
//    blocks issue while other blocks' phase-B waves stall on TA -> A's time
//    mostly disappears under B's TA-bound phase.
//  - Coords (py/px/mask) pass through LDS rows 27..53 of the existing 64-row
//    red buffer (A-reduce uses rows 0..26; final o-reduce reuses all rows
//    only after coords are dead). Saves the 28MB x2 global round-trip.
//
// Block = 512 thr = 256 pixels (2-row strip) x 2 channel-halves.
// __launch_bounds__(512,4): pin VGPR <= 128 so 2 blocks/CU (16 waves) hold.
// ---------------------------------------------------------------------------
__global__ __launch_bounds__(512, 4) void deform_fused_k(
    const float* __restrict__ x,
    const float* __restrict__ wom, const float* __restrict__ b_off,
    const float* __restrict__ b_mod, const float* __restrict__ wt,
    const float* __restrict__ bias, float* __restrict__ out) {
    __shared__ float red[O_ * 256];            // 64 KB

    int b     = blockIdx.x & 7;                // batch -> XCD (L2 locality)
    int strip = blockIdx.x >> 3;               // 0..63 : 2-row strip
    int tid   = threadIdx.x;
    int t     = tid & 255;
    int half  = tid >> 8;
    int c0    = __builtin_amdgcn_readfirstlane(half << 5);  // wave-uniform
    int p     = strip * 256 + t;
    int w     = p & (W_ - 1);
    int h     = p >> 7;

    const float* xb = x + (b * C_ + c0) * HWSZ;

    // ======================= phase A: offset/mask conv =====================
    {
        int offs[9];
        float valid[9];
#pragma unroll
        for (int i = 0; i < 9; i++) {
            int dy = i / 3 - 1, dx = i % 3 - 1;
            int yy = h + dy, xx = w + dx;
            bool v = (yy >= 0 && yy < H_ && xx >= 0 && xx < W_);
            int yc = min(max(yy, 0), H_ - 1);
            int xc = min(max(xx, 0), W_ - 1);
            offs[i] = yc * W_ + xc;
            valid[i] = v ? 1.0f : 0.0f;
        }

        float acc27[27];
#pragma unroll
        for (int o = 0; o < 27; o++) acc27[o] = 0.0f;

        float v[9];
#pragma unroll
        for (int i = 0; i < 9; i++) v[i] = xb[offs[i]] * valid[i];

        for (int c = 0; c < 32; c++) {
            const float* xn = xb + min(c + 1, 31) * HWSZ;
            float vn[9];
#pragma unroll
            for (int i = 0; i < 9; i++) vn[i] = xn[offs[i]] * valid[i];

            const float* wc = wom + (c0 + c) * 243;   // uniform -> s_load
#pragma unroll
            for (int o = 0; o < 27; o++) {
#pragma unroll
                for (int kk = 0; kk < 9; kk++) acc27[o] += v[kk] * wc[o * 9 + kk];
            }
#pragma unroll
            for (int i = 0; i < 9; i++) v[i] = vn[i];
        }

        if (half) {
#pragma unroll
            for (int o = 0; o < 27; o++) red[o * 256 + t] = acc27[o];
        }
        __syncthreads();
        if (!half) {
#pragma unroll
            for (int k = 0; k < 9; k++) {
                float dy = acc27[2 * k]     + red[(2 * k)     * 256 + t] + b_off[2 * k];
                float dx = acc27[2 * k + 1] + red[(2 * k + 1) * 256 + t] + b_off[2 * k + 1];
                float mm = acc27[18 + k]    + red[(18 + k)    * 256 + t] + b_mod[k];
                float mask = 2.0f / (1.0f + __expf(-mm));
                float py = dy + (float)h - 1.0f + (float)(k / 3);
                float px = dx + (float)w - 1.0f + (float)(k % 3);
                // coords -> LDS rows 27..53 (disjoint from A-reduce rows 0..26)
                red[(27 + 3 * k + 0) * 256 + t] = py;
                red[(27 + 3 * k + 1) * 256 + t] = px;
                red[(27 + 3 * k + 2) * 256 + t] = mask;
            }
        }
        __syncthreads();
    }

    // ======================= phase B: sample + GEMM ========================
    float acc[O_];
#pragma unroll
    for (int o = 0; o < O_; o++) acc[o] = 0.0f;

    for (int k = 0; k < 9; k++) {
        float py = red[(27 + 3 * k + 0) * 256 + t];
        float px = red[(27 + 3 * k + 1) * 256 + t];
        float m  = red[(27 + 3 * k + 2) * 256 + t];

        float y0f = floorf(py), x0f = floorf(px);
        float wy = py - y0f, wx = px - x0f;
        int y0 = (int)y0f, x0 = (int)x0f;
        int y1 = y0 + 1;
        float vy0 = (y0 >= 0 && y0 < H_) ? 1.0f : 0.0f;
        float vy1 = (y1 >= 0 && y1 < H_) ? 1.0f : 0.0f;
        float vx0 = (x0 >= 0 && x0 < W_) ? 1.0f : 0.0f;
        float vx1 = (x0 >= -1 && x0 < W_ - 1) ? 1.0f : 0.0f;
        int y0c = min(max(y0, 0), H_ - 1), y1c = min(max(y1, 0), H_ - 1);

        float w00 = (1.0f - wy) * (1.0f - wx) * vy0 * vx0 * m;
        float w01 = (1.0f - wy) * wx * vy0 * vx1 * m;
        float w10 = wy * (1.0f - wx) * vy1 * vx0 * m;
        float w11 = wy * wx * vy1 * vx1 * m;

        // column-pair merge: one 8B load per row covers both x-taps.
        int lc   = min(max(x0, 0), W_ - 2);    // 0..126, load [lc, lc+1]
        bool xlo = (x0 < 0);                   // v01 lives at f.x
        bool xhi = (x0 > W_ - 2);              // v00 lives at f.y
        float a00 = xhi ? 0.0f : (xlo ? w01 : w00);
        float a01 = xlo ? 0.0f : (xhi ? w00 : w01);
        float a10 = xhi ? 0.0f : (xlo ? w11 : w10);
        float a11 = xlo ? 0.0f : (xhi ? w10 : w11);

        int r0 = y0c * W_ + lc;
        int r1 = y1c * W_ + lc;

        const float* wp = wt + k * (C_ * O_) + c0 * O_;   // uniform -> s_load
        for (int c = 0; c < 32; c++) {
            const float* xc = xb + c * HWSZ;
            f2u f0 = *(const f2u*)(xc + r0);
            f2u f1 = *(const f2u*)(xc + r1);
            float s = a00 * f0.x + a01 * f0.y + a10 * f1.x + a11 * f1.y;
            const float* wpc = wp + c * O_;
#pragma unroll
            for (int o = 0; o < O_; o++) acc[o] += s * wpc[o];
        }
    }

    __syncthreads();                           // coords dead; red reusable
    if (half) {
#pragma unroll
        for (int o = 0; o < O_; o++) red[o * 256 + t] = acc[o];  // stride-1
    }
    __syncthreads();
    if (!half) {
        int obase = b * O_ * HWSZ + p;
#pragma unroll
        for (int o = 0; o < O_; o++)
            out[obase + o * HWSZ] = acc[o] + red[o * 256 + t] + bias[o];
    }
}

// ---------------------------------------------------------------------------
extern "C" void kernel_launch(void* const* d_in, const int* in_sizes, int n_in,
                              void* d_out, int out_size, void* d_ws, size_t ws_size,
                              hipStream_t stream) {
    const float* x     = (const float*)d_in[0];
    const float* w_off = (const float*)d_in[1];
    const float* b_off = (const float*)d_in[2];
    const float* w_mod = (const float*)d_in[3];
    const float* b_mod = (const float*)d_in[4];
    const float* w     = (const float*)d_in[5];
    const float* bias  = (const float*)d_in[6];
    float* out = (float*)d_out;

    float* wt  = (float*)d_ws;            // 36,864 floats
    float* wom = wt + K2_ * C_ * O_;      // 15,552 floats

    const int nPrep = K2_ * C_ * O_ + C_ * 243;
    hipLaunchKernelGGL(prep_weights_k, dim3((nPrep + 255) / 256), dim3(256),
                       0, stream, w, w_off, w_mod, wt, wom);
    hipLaunchKernelGGL(deform_fused_k, dim3(512), dim3(512), 0, stream,
                       x, wom, b_off, b_mod, wt, bias, out);
}